// Round 5
// baseline (222.888 us; speedup 1.0000x reference)
//
#include <hip/hip_runtime.h>

// MultiHeadSelfAttention  B=2 S=2048 D=1024 H=16 d=64, fp32 in/out.
// R13: GEMM1 re-tiled to the m97-verified config: 256 threads / 4 waves,
//      each wave owns 64x64 output (f32x4 acc[4][4]) -> 16 MFMA : 8 ds_read
//      per K-step (was 8:6 with 32x64/wave, VGPR=36, 430 TF).
//      Grid 24x32=768 = 3 blocks/CU (3 waves/SIMD TLP).
//   Why: R12 counters: gemm_qkv is now top dispatch (60us, MfmaUtil 16.7%,
//   nothing saturated, VGPR 36 = under-tiled register block).
// attn (R12: QBLK=256/KVBLK=128/8-wave, in-reg softmax), prep, swizzle,
// gemm2 unchanged.
// ws: Ksw 8M @0 | val_h 8M @8M | wq_t 6M @16M | wo_t 2M @22M | qkv 24M @24M
//     | x_h 8M @48M (dead after GEMM1, overwritten by Vsw)

#define D_MODEL 1024
#define NHEAD   16
#define HDIM    64
#define SEQ     2048
#define BATCH   2
#define NTOK    (BATCH * SEQ)

typedef float    f32x4  __attribute__((ext_vector_type(4)));
typedef float    f32x16 __attribute__((ext_vector_type(16)));
typedef _Float16 f16x8  __attribute__((ext_vector_type(8)));
typedef _Float16 f16x4  __attribute__((ext_vector_type(4)));

#define GLOBAL_LOAD_LDS16(gptr, lptr)                                            \
    __builtin_amdgcn_global_load_lds(                                            \
        (const __attribute__((address_space(1))) unsigned int*)(gptr),           \
        (__attribute__((address_space(3))) unsigned int*)(lptr), 16, 0, 0)

// ---------------- prep: x->fp16, W_qkv^T, W_out^T (one launch) ----------------
__global__ __launch_bounds__(256) void prep_kernel(
    const float* __restrict__ x, _Float16* __restrict__ xh,
    const float* __restrict__ Wqkv, _Float16* __restrict__ wq_t,
    const float* __restrict__ Wout, _Float16* __restrict__ wo_t)
{
    const int bx = blockIdx.x;
    const int tid = threadIdx.x;
    if (bx < 4096) {
        const int i = (bx * 256 + tid) * 4;
        const float4 v = *(const float4*)&x[i];
        f16x4 hh;
        hh[0] = (_Float16)v.x; hh[1] = (_Float16)v.y;
        hh[2] = (_Float16)v.z; hh[3] = (_Float16)v.w;
        *(f16x4*)&xh[i] = hh;
        return;
    }
    __shared__ float ts[64][65];
    const float* W; _Float16* Wt; int N, n0, k0;
    if (bx < 4096 + 768) {
        const int local = bx - 4096;
        W = Wqkv; Wt = wq_t; N = 3072;
        n0 = (local % 48) * 64; k0 = (local / 48) * 64;
    } else {
        const int local = bx - 4864;
        W = Wout; Wt = wo_t; N = 1024;
        n0 = (local % 16) * 64; k0 = (local / 16) * 64;
    }
    {
        const int r = tid >> 2, c = (tid & 3) << 4;
        const float* src = W + (size_t)(k0 + r) * N + n0 + c;
        #pragma unroll
        for (int u = 0; u < 4; ++u)
            *(float4*)&ts[r][c + u * 4] = *(const float4*)&src[u * 4];
    }
    __syncthreads();
    {
        const int n = tid >> 2, kg = (tid & 3) << 4;
        f16x8 v0, v1;
        #pragma unroll
        for (int j = 0; j < 8; ++j) {
            v0[j] = (_Float16)ts[kg + j][n];
            v1[j] = (_Float16)ts[kg + 8 + j][n];
        }
        _Float16* dst = Wt + (size_t)(n0 + n) * D_MODEL + k0 + kg;
        *(f16x8*)&dst[0] = v0;
        *(f16x8*)&dst[8] = v1;
    }
}

// ---------------- GEMM1: 128x128 tile, BK=32, 256 threads (4 waves of 64x64) ----------------
// m97-verified config: 16 MFMA : 8 ds_read_b128 per wave per K-step (2:1),
// 4x4 f32x4 acc (64 VGPR). Staging identical byte-pattern, 4 segs/wave.
__global__ __launch_bounds__(256) void gemm_qkv_kernel(
    const _Float16* __restrict__ A, const _Float16* __restrict__ Bt,
    const float* __restrict__ bias, _Float16* __restrict__ Cout,
    int M, int N, int K)
{
    __shared__ _Float16 lds[2][4096];     // A plane 8KB, B plane 8KB: [chunk4][row128][8]
    const int tid = threadIdx.x;
    const int wave = tid >> 6, lane = tid & 63;
    const int quad = lane >> 4, l16 = lane & 15;
    const int m0 = blockIdx.y * 128, n0 = blockIdx.x * 128;
    const int wr = wave >> 1, wc = wave & 1;       // wave tile: 64x64 at (wr*64, wc*64)

    f32x4 acc[4][4] = {};

    for (int k0 = 0; k0 < K; k0 += 32) {
        __syncthreads();
        // 16 wave-segments of 1KB: segs 0-7 = A plane, 8-15 = B plane; 4/wave.
        #pragma unroll
        for (int j = 0; j < 4; ++j) {
            const int seg = wave * 4 + j;          // 0..15 (wave-uniform plane)
            const int s = seg & 7;
            const int chunk = s >> 1;
            const int row = ((s & 1) << 6) | lane;
            const _Float16* gsrc = (seg < 8) ? (A + (size_t)(m0 + row) * K)
                                             : (Bt + (size_t)(n0 + row) * K);
            GLOBAL_LOAD_LDS16(gsrc + k0 + chunk * 8, &lds[seg >> 3][s * 512]);
        }
        __syncthreads();

        f16x8 a[4], b[4];
        #pragma unroll
        for (int mt = 0; mt < 4; ++mt)
            a[mt] = *(const f16x8*)&lds[0][quad * 1024 + (wr * 64 + mt * 16 + l16) * 8];
        #pragma unroll
        for (int nt = 0; nt < 4; ++nt)
            b[nt] = *(const f16x8*)&lds[1][quad * 1024 + (wc * 64 + nt * 16 + l16) * 8];
        #pragma unroll
        for (int mt = 0; mt < 4; ++mt)
            #pragma unroll
            for (int nt = 0; nt < 4; ++nt)
                acc[mt][nt] = __builtin_amdgcn_mfma_f32_16x16x32_f16(a[mt], b[nt], acc[mt][nt], 0, 0, 0);
    }

    #pragma unroll
    for (int nt = 0; nt < 4; ++nt) {
        const int col = n0 + wc * 64 + nt * 16 + l16;
        const float bv = bias[col];
        #pragma unroll
        for (int mt = 0; mt < 4; ++mt) {
            #pragma unroll
            for (int r = 0; r < 4; ++r) {
                const int row = m0 + wr * 64 + mt * 16 + quad * 4 + r;
                Cout[(size_t)row * N + col] = (_Float16)(acc[mt][nt][r] + bv);
            }
        }
    }
}

// ---------------- GEMM2: 128x64 tile, BK=32, 512 threads (8 waves of 32x32), fp32 out ----------------
__global__ __launch_bounds__(512) void gemm_out_kernel(
    const _Float16* __restrict__ A, const _Float16* __restrict__ Bt,
    const float* __restrict__ bias, float* __restrict__ Cout)
{
    const int K = D_MODEL, N = D_MODEL;
    __shared__ _Float16 ldsA[4096];       // [chunk4][row128][8] 8KB
    __shared__ _Float16 ldsB[2048];       // [chunk4][row64][8]  4KB
    const int tid = threadIdx.x;
    const int wave = tid >> 6, lane = tid & 63;
    const int quad = lane >> 4, l16 = lane & 15;
    const int m0 = blockIdx.y * 128, n0 = blockIdx.x * 64;
    const int wr = wave >> 1, wc = wave & 1;       // wave tile: rows wr*32, cols wc*32

    f32x4 acc[2][2] = {};

    for (int k0 = 0; k0 < K; k0 += 32) {
        __syncthreads();
        if (wave < 4) {
            #pragma unroll
            for (int j = 0; j < 2; ++j) {
                const int seg = wave * 2 + j;          // 0..7
                const int chunk = seg >> 1;
                const int row = ((seg & 1) << 6) | lane;
                GLOBAL_LOAD_LDS16(A + (size_t)(m0 + row) * K + k0 + chunk * 8, ldsA + seg * 512);
            }
        } else {
            const int seg = wave - 4;                  // 0..3 (chunk = seg, 64 rows)
            GLOBAL_LOAD_LDS16(Bt + (size_t)(n0 + lane) * K + k0 + seg * 8, ldsB + seg * 512);
        }
        __syncthreads();

        f16x8 a[2], b[2];
        #pragma unroll
        for (int mt = 0; mt < 2; ++mt)
            a[mt] = *(const f16x8*)&ldsA[quad * 1024 + (wr * 32 + mt * 16 + l16) * 8];
        #pragma unroll
        for (int nt = 0; nt < 2; ++nt)
            b[nt] = *(const f16x8*)&ldsB[quad * 512 + (wc * 32 + nt * 16 + l16) * 8];
        #pragma unroll
        for (int mt = 0; mt < 2; ++mt)
            #pragma unroll
            for (int nt = 0; nt < 2; ++nt)
                acc[mt][nt] = __builtin_amdgcn_mfma_f32_16x16x32_f16(a[mt], b[nt], acc[mt][nt], 0, 0, 0);
    }

    #pragma unroll
    for (int nt = 0; nt < 2; ++nt) {
        const int col = n0 + wc * 32 + nt * 16 + l16;
        const float bv = bias[col];
        #pragma unroll
        for (int mt = 0; mt < 2; ++mt) {
            #pragma unroll
            for (int r = 0; r < 4; ++r) {
                const int row = m0 + wr * 32 + mt * 16 + quad * 4 + r;
                Cout[(size_t)row * N + col] = acc[mt][nt][r] + bv;
            }
        }
    }
}

// ---------------- K,V slices of qkv -> swizzled MFMA-ready layouts ----------------
__global__ __launch_bounds__(256) void swizzle_kv_kernel(
    const _Float16* __restrict__ qkv,
    _Float16* __restrict__ Ksw, _Float16* __restrict__ Vsw)
{
    __shared__ _Float16 ts[64][72];
    const int tid = threadIdx.x;
    const int s0 = blockIdx.x * 64, h = blockIdx.y, b = blockIdx.z;
    const size_t hsz = (size_t)8 * SEQ * 8;
    _Float16* kh = Ksw + (size_t)(b * NHEAD + h) * hsz;
    _Float16* vh = Vsw + (size_t)(b * NHEAD + h) * hsz;

    {
        const int s = s0 + (tid >> 2);
        const int dg = (tid & 3) << 4;
        const _Float16* src = qkv + (size_t)(b * SEQ + s) * (3 * D_MODEL) + h * (3 * HDIM) + HDIM + dg;
        const f16x8 v0 = *(const f16x8*)&src[0];
        const f16x8 v1 = *(const f16x8*)&src[8];
        const int c0 = dg >> 3;
        *(f16x8*)&kh[((size_t)c0 * SEQ + s) * 8]       = v0;
        *(f16x8*)&kh[((size_t)(c0 + 1) * SEQ + s) * 8] = v1;
    }
    {
        const int s = tid >> 2, dg = (tid & 3) << 4;
        const _Float16* src = qkv + (size_t)(b * SEQ + s0 + s) * (3 * D_MODEL) + h * (3 * HDIM) + 2 * HDIM + dg;
        *(f16x8*)&ts[s][dg]     = *(const f16x8*)&src[0];
        *(f16x8*)&ts[s][dg + 8] = *(const f16x8*)&src[8];
    }
    __syncthreads();
    {
        const int d = tid >> 2, sg = (tid & 3) << 4;
        f16x8 v0, v1;
        #pragma unroll
        for (int j = 0; j < 8; ++j) { v0[j] = ts[sg + j][d]; v1[j] = ts[sg + 8 + j][d]; }
        const int cs0 = (s0 + sg) >> 3;
        *(f16x8*)&vh[((size_t)cs0 * HDIM + d) * 8]       = v0;
        *(f16x8*)&vh[((size_t)(cs0 + 1) * HDIM + d) * 8] = v1;
    }
}

// softmax fragment: s0/s1 (keys 0-31 / 32-63 scores for q=l31) -> 4 PV A-frags
// pa[ks][j] = P[q=l31][key = ks*16 + hi*8 + j], rs += sum of own 32 exp2's.
__device__ __forceinline__ void softmax_frag(
    const f32x16 s0, const f32x16 s1, float& rs, f16x8 pa[4])
{
    #pragma unroll
    for (int half = 0; half < 2; ++half) {
        const f32x16 sv = half ? s1 : s0;
        float p[16];
        #pragma unroll
        for (int r = 0; r < 16; ++r)
            p[r] = __builtin_amdgcn_exp2f(sv[r]);
        #pragma unroll
        for (int r = 0; r < 16; r += 4)
            rs += (p[r] + p[r + 1]) + (p[r + 2] + p[r + 3]);

        union { f16x8 hv; unsigned u[4]; } lo, hh;
        {
            const unsigned A = __builtin_bit_cast(unsigned, __builtin_amdgcn_cvt_pkrtz(p[0], p[1]));
            const unsigned B = __builtin_bit_cast(unsigned, __builtin_amdgcn_cvt_pkrtz(p[2], p[3]));
            const unsigned C = __builtin_bit_cast(unsigned, __builtin_amdgcn_cvt_pkrtz(p[4], p[5]));
            const unsigned D = __builtin_bit_cast(unsigned, __builtin_amdgcn_cvt_pkrtz(p[6], p[7]));
            const auto rac = __builtin_amdgcn_permlane32_swap(A, C, false, false);
            const auto rbd = __builtin_amdgcn_permlane32_swap(B, D, false, false);
            lo.u[0] = rac[0]; lo.u[1] = rbd[0]; lo.u[2] = rac[1]; lo.u[3] = rbd[1];
        }
        {
            const unsigned E = __builtin_bit_cast(unsigned, __builtin_amdgcn_cvt_pkrtz(p[8],  p[9]));
            const unsigned F = __builtin_bit_cast(unsigned, __builtin_amdgcn_cvt_pkrtz(p[10], p[11]));
            const unsigned G = __builtin_bit_cast(unsigned, __builtin_amdgcn_cvt_pkrtz(p[12], p[13]));
            const unsigned H = __builtin_bit_cast(unsigned, __builtin_amdgcn_cvt_pkrtz(p[14], p[15]));
            const auto reg = __builtin_amdgcn_permlane32_swap(E, G, false, false);
            const auto rfh = __builtin_amdgcn_permlane32_swap(F, H, false, false);
            hh.u[0] = reg[0]; hh.u[1] = rfh[0]; hh.u[2] = reg[1]; hh.u[3] = rfh[1];
        }
        pa[half * 2]     = lo.hv;
        pa[half * 2 + 1] = hh.hv;
    }
}

// ---------------- fp16 MFMA flash attention, 32x32, QBLK=256 (8 waves x 32q),
//                  KVBLK=128 (2x 64-key subtiles per barrier), dbuf K/V --------
__global__ __launch_bounds__(512) void attn_mfma_kernel(
    const _Float16* __restrict__ qkv,
    const _Float16* __restrict__ Ksw, const _Float16* __restrict__ Vsw,
    _Float16* __restrict__ val)
{
    __shared__ _Float16 Ks[2][8192];      // [sub2][dchunk8][key64][8]  16KB x2
    __shared__ _Float16 Vts[2][8192];     // [sub2][kchunk8][d64][8]    16KB x2

    const int tid = threadIdx.x;
    const int wave = tid >> 6, lane = tid & 63;
    const int l31 = lane & 31, hi = lane >> 5;

    // XCD-chunked swizzle: 256 blocks, 32/XCD = 4 heads x 8 qt -> K/V 2MB/XCD
    const int id = blockIdx.x;
    const int g  = (id & 7) * 32 + (id >> 3);
    const int qt = g & 7, hb = g >> 3;
    const int h  = hb & 15, b = hb >> 4;
    const int q0 = qt * 256;

    const size_t hsz = (size_t)8 * SEQ * 8;
    const _Float16* kh = Ksw + (size_t)(b * NHEAD + h) * hsz;
    const _Float16* vh = Vsw + (size_t)(b * NHEAD + h) * hsz;

    // Q B-fragments: col=l31 -> q row, k = kk*16 + hi*8 + j
    f16x8 qf[4];
    {
        const int row = q0 + wave * 32 + l31;
        const _Float16* src = qkv + (size_t)(b * SEQ + row) * (3 * D_MODEL) + h * (3 * HDIM) + hi * 8;
        #pragma unroll
        for (int kk = 0; kk < 4; ++kk) {
            const f16x8 t = *(const f16x8*)(src + kk * 16);
            #pragma unroll
            for (int j = 0; j < 8; ++j)
                qf[kk][j] = (_Float16)((float)t[j] * 0.1803368802f);   // (1/8)*log2(e)
        }
    }

    f32x16 acc0 = {};      // O[q][d], dtile 0 (d = l31)
    f32x16 acc1 = {};      // dtile 1 (d = 32+l31)
    float rs = 0.f;

    // staging: 8 waves x 2 chunk-instrs each cover sub(2) x chunk(8) for K and V
    const int sidx0 = wave * 2;            // 0..14 even
    // prologue: stage 128-key tile 0 into buffer 0
    #pragma unroll
    for (int j = 0; j < 2; ++j) {
        const int idx = sidx0 + j;         // 0..15
        const int u = idx >> 3, c = idx & 7;
        GLOBAL_LOAD_LDS16(kh + ((size_t)c * SEQ + u * 64 + lane) * 8, &Ks[0][idx * 512]);
        GLOBAL_LOAD_LDS16(vh + ((size_t)(u * 8 + c) * HDIM + lane) * 8, &Vts[0][idx * 512]);
    }
    __syncthreads();

    for (int kt = 0; kt < SEQ / 128; ++kt) {
        const int cur = kt & 1;

        // stage tile kt+1 into the other buffer
        if (kt + 1 < SEQ / 128) {
            #pragma unroll
            for (int j = 0; j < 2; ++j) {
                const int idx = sidx0 + j;
                const int u = idx >> 3, c = idx & 7;
                GLOBAL_LOAD_LDS16(kh + ((size_t)c * SEQ + (kt + 1) * 128 + u * 64 + lane) * 8,
                                  &Ks[cur ^ 1][idx * 512]);
                GLOBAL_LOAD_LDS16(vh + ((size_t)((kt + 1) * 16 + u * 8 + c) * HDIM + lane) * 8,
                                  &Vts[cur ^ 1][idx * 512]);
            }
        }

        // ---- two 64-key subtiles ----
        #pragma unroll
        for (int u = 0; u < 2; ++u) {
            const _Float16* ksub = &Ks[cur][u * 4096];
            const _Float16* vsub = &Vts[cur][u * 4096];

            // QK^T: S^T tiles (keytile 0: keys 0-31, keytile 1: keys 32-63)
            f32x16 s0 = {}, s1 = {};
            __builtin_amdgcn_s_setprio(1);
            #pragma unroll
            for (int kk = 0; kk < 4; ++kk) {
                const f16x8 k0 = *(const f16x8*)&ksub[(kk * 2 + hi) * 512 + l31 * 8];
                const f16x8 k1 = *(const f16x8*)&ksub[(kk * 2 + hi) * 512 + (32 + l31) * 8];
                s0 = __builtin_amdgcn_mfma_f32_32x32x16_f16(k0, qf[kk], s0, 0, 0, 0);
                s1 = __builtin_amdgcn_mfma_f32_32x32x16_f16(k1, qf[kk], s1, 0, 0, 0);
            }
            __builtin_amdgcn_s_setprio(0);

            // exp2 + in-register transpose to PV A-frags
            f16x8 pa[4];
            softmax_frag(s0, s1, rs, pa);

            // PV: O[q][d] += P[q][k] V[k][d], 4 ksteps of 16 keys
            __builtin_amdgcn_s_setprio(1);
            #pragma unroll
            for (int ks = 0; ks < 4; ++ks) {
                const f16x8 v0 = *(const f16x8*)&vsub[(ks * 2 + hi) * 512 + l31 * 8];
                const f16x8 v1 = *(const f16x8*)&vsub[(ks * 2 + hi) * 512 + (32 + l31) * 8];
                acc0 = __builtin_amdgcn_mfma_f32_32x32x16_f16(pa[ks], v0, acc0, 0, 0, 0);
                acc1 = __builtin_amdgcn_mfma_f32_32x32x16_f16(pa[ks], v1, acc1, 0, 0, 0);
            }
            __builtin_amdgcn_s_setprio(0);
        }

        __syncthreads();
    }

    // lane covers half the keys for q=l31; partner lane^32 has the complement
    rs += __shfl_xor(rs, 32);
    const float inv = 1.f / rs;

    #pragma unroll
    for (int r = 0; r < 16; ++r) {
        const int qo = (r & 3) + 8 * (r >> 2) + 4 * hi;     // wave-local q row
        const float invr = __shfl(inv, qo);                  // lane qo holds inv for q=qo
        const int row = b * SEQ + q0 + wave * 32 + qo;
        val[(size_t)row * D_MODEL + h * HDIM + l31]      = (_Float16)(acc0[r] * invr);
        val[(size_t)row * D_MODEL + h * HDIM + 32 + l31] = (_Float16)(acc1[r] * invr);
    }
}

extern "C" void kernel_launch(void* const* d_in, const int* in_sizes, int n_in,
                              void* d_out, int out_size, void* d_ws, size_t ws_size,
                              hipStream_t stream)
{
    const float* x     = (const float*)d_in[0];
    const float* W_qkv = (const float*)d_in[1];
    const float* b_qkv = (const float*)d_in[2];
    const float* W_out = (const float*)d_in[3];
    const float* b_out = (const float*)d_in[4];

    char* ws = (char*)d_ws;
    _Float16* Ksw   = (_Float16*)ws;                      // [32][8][2048][8]  8 MiB
    _Float16* val_h = (_Float16*)(ws + (8u << 20));       // [4096][1024]      8 MiB
    _Float16* wq_t  = (_Float16*)(ws + (16u << 20));      // [3072][1024]      6 MiB
    _Float16* wo_t  = (_Float16*)(ws + (22u << 20));      // [1024][1024]      2 MiB
    _Float16* qkv_h = (_Float16*)(ws + (24u << 20));      // [4096][3072]     24 MiB
    _Float16* x_h   = (_Float16*)(ws + (48u << 20));      // [4096][1024]      8 MiB
    _Float16* Vsw   = (_Float16*)(ws + (48u << 20));      // overwrites dead x_h

    prep_kernel<<<5120, 256, 0, stream>>>(x, x_h, W_qkv, wq_t, W_out, wo_t);
    gemm_qkv_kernel<<<dim3(3 * D_MODEL / 128, NTOK / 128), 256, 0, stream>>>(
        x_h, wq_t, b_qkv, qkv_h, NTOK, 3 * D_MODEL, D_MODEL);
    swizzle_kv_kernel<<<dim3(SEQ / 64, NHEAD, BATCH), 256, 0, stream>>>(qkv_h, Ksw, Vsw);
    attn_mfma_kernel<<<dim3(256, 1, 1), 512, 0, stream>>>(qkv_h, Ksw, Vsw, val_h);
    gemm_out_kernel<<<dim3(D_MODEL / 64, NTOK / 128), 512, 0, stream>>>(
        val_h, wo_t, b_out, (float*)d_out);
}

// Round 6
// 216.817 us; speedup vs baseline: 1.0280x; 1.0280x over previous
//
#include <hip/hip_runtime.h>

// MultiHeadSelfAttention  B=2 S=2048 D=1024 H=16 d=64, fp32 in/out.
// R14: GEMM1 reverted to R12's 8-wave 32x64/wave config (R13's 4-wave 64x64
//      regressed: Occ 54->30%, K=1024 is barrier-stall-bound not ratio-bound)
//      + double-buffered LDS staging, ONE barrier per K-step (stage t+1
//      before compute t) -- the same dbuf pattern verified in attn R12.
//      Same graft applied to GEMM2.
//   Why: R12 GEMM1 serialized ~200-500cy load latency into each of 32
//   K-steps; dbuf moves it off the critical path; 24 waves/CU cover the rest.
// attn (R12: QBLK=256/KVBLK=128/8-wave, in-reg softmax), prep, swizzle
// unchanged.
// ws: Ksw 8M @0 | val_h 8M @8M | wq_t 6M @16M | wo_t 2M @22M | qkv 24M @24M
//     | x_h 8M @48M (dead after GEMM1, overwritten by Vsw)

#define D_MODEL 1024
#define NHEAD   16
#define HDIM    64
#define SEQ     2048
#define BATCH   2
#define NTOK    (BATCH * SEQ)

typedef float    f32x4  __attribute__((ext_vector_type(4)));
typedef float    f32x16 __attribute__((ext_vector_type(16)));
typedef _Float16 f16x8  __attribute__((ext_vector_type(8)));
typedef _Float16 f16x4  __attribute__((ext_vector_type(4)));

#define GLOBAL_LOAD_LDS16(gptr, lptr)                                            \
    __builtin_amdgcn_global_load_lds(                                            \
        (const __attribute__((address_space(1))) unsigned int*)(gptr),           \
        (__attribute__((address_space(3))) unsigned int*)(lptr), 16, 0, 0)

// ---------------- prep: x->fp16, W_qkv^T, W_out^T (one launch) ----------------
__global__ __launch_bounds__(256) void prep_kernel(
    const float* __restrict__ x, _Float16* __restrict__ xh,
    const float* __restrict__ Wqkv, _Float16* __restrict__ wq_t,
    const float* __restrict__ Wout, _Float16* __restrict__ wo_t)
{
    const int bx = blockIdx.x;
    const int tid = threadIdx.x;
    if (bx < 4096) {
        const int i = (bx * 256 + tid) * 4;
        const float4 v = *(const float4*)&x[i];
        f16x4 hh;
        hh[0] = (_Float16)v.x; hh[1] = (_Float16)v.y;
        hh[2] = (_Float16)v.z; hh[3] = (_Float16)v.w;
        *(f16x4*)&xh[i] = hh;
        return;
    }
    __shared__ float ts[64][65];
    const float* W; _Float16* Wt; int N, n0, k0;
    if (bx < 4096 + 768) {
        const int local = bx - 4096;
        W = Wqkv; Wt = wq_t; N = 3072;
        n0 = (local % 48) * 64; k0 = (local / 48) * 64;
    } else {
        const int local = bx - 4864;
        W = Wout; Wt = wo_t; N = 1024;
        n0 = (local % 16) * 64; k0 = (local / 16) * 64;
    }
    {
        const int r = tid >> 2, c = (tid & 3) << 4;
        const float* src = W + (size_t)(k0 + r) * N + n0 + c;
        #pragma unroll
        for (int u = 0; u < 4; ++u)
            *(float4*)&ts[r][c + u * 4] = *(const float4*)&src[u * 4];
    }
    __syncthreads();
    {
        const int n = tid >> 2, kg = (tid & 3) << 4;
        f16x8 v0, v1;
        #pragma unroll
        for (int j = 0; j < 8; ++j) {
            v0[j] = (_Float16)ts[kg + j][n];
            v1[j] = (_Float16)ts[kg + 8 + j][n];
        }
        _Float16* dst = Wt + (size_t)(n0 + n) * D_MODEL + k0 + kg;
        *(f16x8*)&dst[0] = v0;
        *(f16x8*)&dst[8] = v1;
    }
}

// ---------------- GEMM1: 128x128 tile, BK=32, 512 threads (8 waves of 32x64),
//                  double-buffered staging, one barrier per K-step ------------
__global__ __launch_bounds__(512) void gemm_qkv_kernel(
    const _Float16* __restrict__ A, const _Float16* __restrict__ Bt,
    const float* __restrict__ bias, _Float16* __restrict__ Cout,
    int M, int N, int K)
{
    __shared__ _Float16 lds[2][2][4096];  // [buf][plane A/B][chunk4][row128][8]
    const int tid = threadIdx.x;
    const int wave = tid >> 6, lane = tid & 63;
    const int quad = lane >> 4, l16 = lane & 15;
    const int m0 = blockIdx.y * 128, n0 = blockIdx.x * 128;
    const int wr = wave >> 1, wc = wave & 1;       // wave tile: rows wr*32, cols wc*64

    f32x4 acc[2][4] = {};

    const bool isA = wave < 4;
    const _Float16* gsrc = isA ? (A + (size_t)m0 * K) : (Bt + (size_t)n0 * K);
    const int plane = isA ? 0 : 1;
    const int sbase = (wave & 3) * 2;              // 2 segments of 1KB per wave

    // prologue: stage K-tile 0 into buf 0
    #pragma unroll
    for (int j = 0; j < 2; ++j) {
        const int seg = sbase + j;
        const int chunk = seg >> 1;
        const int row = ((seg & 1) << 6) | lane;
        GLOBAL_LOAD_LDS16(gsrc + (size_t)row * K + chunk * 8, &lds[0][plane][seg * 512]);
    }
    __syncthreads();

    const int nk = K / 32;
    for (int t = 0; t < nk; ++t) {
        const int cur = t & 1;

        // stage K-tile t+1 into the other buffer (readers of that buffer
        // finished before the end-of-(t-1) barrier; end-of-t barrier drains
        // vmcnt before it is read)
        if (t + 1 < nk) {
            const int k1 = (t + 1) * 32;
            #pragma unroll
            for (int j = 0; j < 2; ++j) {
                const int seg = sbase + j;
                const int chunk = seg >> 1;
                const int row = ((seg & 1) << 6) | lane;
                GLOBAL_LOAD_LDS16(gsrc + (size_t)row * K + k1 + chunk * 8,
                                  &lds[cur ^ 1][plane][seg * 512]);
            }
        }

        f16x8 a[2], b[4];
        #pragma unroll
        for (int mt = 0; mt < 2; ++mt)
            a[mt] = *(const f16x8*)&lds[cur][0][quad * 1024 + (wr * 32 + mt * 16 + l16) * 8];
        #pragma unroll
        for (int nt = 0; nt < 4; ++nt)
            b[nt] = *(const f16x8*)&lds[cur][1][quad * 1024 + (wc * 64 + nt * 16 + l16) * 8];
        #pragma unroll
        for (int mt = 0; mt < 2; ++mt)
            #pragma unroll
            for (int nt = 0; nt < 4; ++nt)
                acc[mt][nt] = __builtin_amdgcn_mfma_f32_16x16x32_f16(a[mt], b[nt], acc[mt][nt], 0, 0, 0);

        __syncthreads();
    }

    #pragma unroll
    for (int nt = 0; nt < 4; ++nt) {
        const int col = n0 + wc * 64 + nt * 16 + l16;
        const float bv = bias[col];
        #pragma unroll
        for (int mt = 0; mt < 2; ++mt) {
            #pragma unroll
            for (int r = 0; r < 4; ++r) {
                const int row = m0 + wr * 32 + mt * 16 + quad * 4 + r;
                Cout[(size_t)row * N + col] = (_Float16)(acc[mt][nt][r] + bv);
            }
        }
    }
}

// ---------------- GEMM2: 128x64 tile, BK=32, 512 threads (8 waves of 32x32),
//                  double-buffered staging, one barrier per K-step, fp32 out --
__global__ __launch_bounds__(512) void gemm_out_kernel(
    const _Float16* __restrict__ A, const _Float16* __restrict__ Bt,
    const float* __restrict__ bias, float* __restrict__ Cout)
{
    const int K = D_MODEL, N = D_MODEL;
    __shared__ _Float16 ldsA[2][4096];    // [buf][chunk4][row128][8] 8KB x2
    __shared__ _Float16 ldsB[2][2048];    // [buf][chunk4][row64][8]  4KB x2
    const int tid = threadIdx.x;
    const int wave = tid >> 6, lane = tid & 63;
    const int quad = lane >> 4, l16 = lane & 15;
    const int m0 = blockIdx.y * 128, n0 = blockIdx.x * 64;
    const int wr = wave >> 1, wc = wave & 1;       // wave tile: rows wr*32, cols wc*32

    f32x4 acc[2][2] = {};

    // prologue: stage K-tile 0 into buf 0
    if (wave < 4) {
        #pragma unroll
        for (int j = 0; j < 2; ++j) {
            const int seg = wave * 2 + j;
            const int chunk = seg >> 1;
            const int row = ((seg & 1) << 6) | lane;
            GLOBAL_LOAD_LDS16(A + (size_t)(m0 + row) * K + chunk * 8, &ldsA[0][seg * 512]);
        }
    } else {
        const int seg = wave - 4;
        GLOBAL_LOAD_LDS16(Bt + (size_t)(n0 + lane) * K + seg * 8, &ldsB[0][seg * 512]);
    }
    __syncthreads();

    const int nk = K / 32;
    for (int t = 0; t < nk; ++t) {
        const int cur = t & 1;

        if (t + 1 < nk) {
            const int k1 = (t + 1) * 32;
            if (wave < 4) {
                #pragma unroll
                for (int j = 0; j < 2; ++j) {
                    const int seg = wave * 2 + j;
                    const int chunk = seg >> 1;
                    const int row = ((seg & 1) << 6) | lane;
                    GLOBAL_LOAD_LDS16(A + (size_t)(m0 + row) * K + k1 + chunk * 8,
                                      &ldsA[cur ^ 1][seg * 512]);
                }
            } else {
                const int seg = wave - 4;
                GLOBAL_LOAD_LDS16(Bt + (size_t)(n0 + lane) * K + k1 + seg * 8,
                                  &ldsB[cur ^ 1][seg * 512]);
            }
        }

        f16x8 a[2], b[2];
        #pragma unroll
        for (int mt = 0; mt < 2; ++mt)
            a[mt] = *(const f16x8*)&ldsA[cur][quad * 1024 + (wr * 32 + mt * 16 + l16) * 8];
        #pragma unroll
        for (int nt = 0; nt < 2; ++nt)
            b[nt] = *(const f16x8*)&ldsB[cur][quad * 512 + (wc * 32 + nt * 16 + l16) * 8];
        #pragma unroll
        for (int mt = 0; mt < 2; ++mt)
            #pragma unroll
            for (int nt = 0; nt < 2; ++nt)
                acc[mt][nt] = __builtin_amdgcn_mfma_f32_16x16x32_f16(a[mt], b[nt], acc[mt][nt], 0, 0, 0);

        __syncthreads();
    }

    #pragma unroll
    for (int nt = 0; nt < 2; ++nt) {
        const int col = n0 + wc * 32 + nt * 16 + l16;
        const float bv = bias[col];
        #pragma unroll
        for (int mt = 0; mt < 2; ++mt) {
            #pragma unroll
            for (int r = 0; r < 4; ++r) {
                const int row = m0 + wr * 32 + mt * 16 + quad * 4 + r;
                Cout[(size_t)row * N + col] = acc[mt][nt][r] + bv;
            }
        }
    }
}

// ---------------- K,V slices of qkv -> swizzled MFMA-ready layouts ----------------
__global__ __launch_bounds__(256) void swizzle_kv_kernel(
    const _Float16* __restrict__ qkv,
    _Float16* __restrict__ Ksw, _Float16* __restrict__ Vsw)
{
    __shared__ _Float16 ts[64][72];
    const int tid = threadIdx.x;
    const int s0 = blockIdx.x * 64, h = blockIdx.y, b = blockIdx.z;
    const size_t hsz = (size_t)8 * SEQ * 8;
    _Float16* kh = Ksw + (size_t)(b * NHEAD + h) * hsz;
    _Float16* vh = Vsw + (size_t)(b * NHEAD + h) * hsz;

    {
        const int s = s0 + (tid >> 2);
        const int dg = (tid & 3) << 4;
        const _Float16* src = qkv + (size_t)(b * SEQ + s) * (3 * D_MODEL) + h * (3 * HDIM) + HDIM + dg;
        const f16x8 v0 = *(const f16x8*)&src[0];
        const f16x8 v1 = *(const f16x8*)&src[8];
        const int c0 = dg >> 3;
        *(f16x8*)&kh[((size_t)c0 * SEQ + s) * 8]       = v0;
        *(f16x8*)&kh[((size_t)(c0 + 1) * SEQ + s) * 8] = v1;
    }
    {
        const int s = tid >> 2, dg = (tid & 3) << 4;
        const _Float16* src = qkv + (size_t)(b * SEQ + s0 + s) * (3 * D_MODEL) + h * (3 * HDIM) + 2 * HDIM + dg;
        *(f16x8*)&ts[s][dg]     = *(const f16x8*)&src[0];
        *(f16x8*)&ts[s][dg + 8] = *(const f16x8*)&src[8];
    }
    __syncthreads();
    {
        const int d = tid >> 2, sg = (tid & 3) << 4;
        f16x8 v0, v1;
        #pragma unroll
        for (int j = 0; j < 8; ++j) { v0[j] = ts[sg + j][d]; v1[j] = ts[sg + 8 + j][d]; }
        const int cs0 = (s0 + sg) >> 3;
        *(f16x8*)&vh[((size_t)cs0 * HDIM + d) * 8]       = v0;
        *(f16x8*)&vh[((size_t)(cs0 + 1) * HDIM + d) * 8] = v1;
    }
}

// softmax fragment: s0/s1 (keys 0-31 / 32-63 scores for q=l31) -> 4 PV A-frags
// pa[ks][j] = P[q=l31][key = ks*16 + hi*8 + j], rs += sum of own 32 exp2's.
__device__ __forceinline__ void softmax_frag(
    const f32x16 s0, const f32x16 s1, float& rs, f16x8 pa[4])
{
    #pragma unroll
    for (int half = 0; half < 2; ++half) {
        const f32x16 sv = half ? s1 : s0;
        float p[16];
        #pragma unroll
        for (int r = 0; r < 16; ++r)
            p[r] = __builtin_amdgcn_exp2f(sv[r]);
        #pragma unroll
        for (int r = 0; r < 16; r += 4)
            rs += (p[r] + p[r + 1]) + (p[r + 2] + p[r + 3]);

        union { f16x8 hv; unsigned u[4]; } lo, hh;
        {
            const unsigned A = __builtin_bit_cast(unsigned, __builtin_amdgcn_cvt_pkrtz(p[0], p[1]));
            const unsigned B = __builtin_bit_cast(unsigned, __builtin_amdgcn_cvt_pkrtz(p[2], p[3]));
            const unsigned C = __builtin_bit_cast(unsigned, __builtin_amdgcn_cvt_pkrtz(p[4], p[5]));
            const unsigned D = __builtin_bit_cast(unsigned, __builtin_amdgcn_cvt_pkrtz(p[6], p[7]));
            const auto rac = __builtin_amdgcn_permlane32_swap(A, C, false, false);
            const auto rbd = __builtin_amdgcn_permlane32_swap(B, D, false, false);
            lo.u[0] = rac[0]; lo.u[1] = rbd[0]; lo.u[2] = rac[1]; lo.u[3] = rbd[1];
        }
        {
            const unsigned E = __builtin_bit_cast(unsigned, __builtin_amdgcn_cvt_pkrtz(p[8],  p[9]));
            const unsigned F = __builtin_bit_cast(unsigned, __builtin_amdgcn_cvt_pkrtz(p[10], p[11]));
            const unsigned G = __builtin_bit_cast(unsigned, __builtin_amdgcn_cvt_pkrtz(p[12], p[13]));
            const unsigned H = __builtin_bit_cast(unsigned, __builtin_amdgcn_cvt_pkrtz(p[14], p[15]));
            const auto reg = __builtin_amdgcn_permlane32_swap(E, G, false, false);
            const auto rfh = __builtin_amdgcn_permlane32_swap(F, H, false, false);
            hh.u[0] = reg[0]; hh.u[1] = rfh[0]; hh.u[2] = reg[1]; hh.u[3] = rfh[1];
        }
        pa[half * 2]     = lo.hv;
        pa[half * 2 + 1] = hh.hv;
    }
}

// ---------------- fp16 MFMA flash attention, 32x32, QBLK=256 (8 waves x 32q),
//                  KVBLK=128 (2x 64-key subtiles per barrier), dbuf K/V --------
__global__ __launch_bounds__(512) void attn_mfma_kernel(
    const _Float16* __restrict__ qkv,
    const _Float16* __restrict__ Ksw, const _Float16* __restrict__ Vsw,
    _Float16* __restrict__ val)
{
    __shared__ _Float16 Ks[2][8192];      // [sub2][dchunk8][key64][8]  16KB x2
    __shared__ _Float16 Vts[2][8192];     // [sub2][kchunk8][d64][8]    16KB x2

    const int tid = threadIdx.x;
    const int wave = tid >> 6, lane = tid & 63;
    const int l31 = lane & 31, hi = lane >> 5;

    // XCD-chunked swizzle: 256 blocks, 32/XCD = 4 heads x 8 qt -> K/V 2MB/XCD
    const int id = blockIdx.x;
    const int g  = (id & 7) * 32 + (id >> 3);
    const int qt = g & 7, hb = g >> 3;
    const int h  = hb & 15, b = hb >> 4;
    const int q0 = qt * 256;

    const size_t hsz = (size_t)8 * SEQ * 8;
    const _Float16* kh = Ksw + (size_t)(b * NHEAD + h) * hsz;
    const _Float16* vh = Vsw + (size_t)(b * NHEAD + h) * hsz;

    // Q B-fragments: col=l31 -> q row, k = kk*16 + hi*8 + j
    f16x8 qf[4];
    {
        const int row = q0 + wave * 32 + l31;
        const _Float16* src = qkv + (size_t)(b * SEQ + row) * (3 * D_MODEL) + h * (3 * HDIM) + hi * 8;
        #pragma unroll
        for (int kk = 0; kk < 4; ++kk) {
            const f16x8 t = *(const f16x8*)(src + kk * 16);
            #pragma unroll
            for (int j = 0; j < 8; ++j)
                qf[kk][j] = (_Float16)((float)t[j] * 0.1803368802f);   // (1/8)*log2(e)
        }
    }

    f32x16 acc0 = {};      // O[q][d], dtile 0 (d = l31)
    f32x16 acc1 = {};      // dtile 1 (d = 32+l31)
    float rs = 0.f;

    // staging: 8 waves x 2 chunk-instrs each cover sub(2) x chunk(8) for K and V
    const int sidx0 = wave * 2;            // 0..14 even
    // prologue: stage 128-key tile 0 into buffer 0
    #pragma unroll
    for (int j = 0; j < 2; ++j) {
        const int idx = sidx0 + j;         // 0..15
        const int u = idx >> 3, c = idx & 7;
        GLOBAL_LOAD_LDS16(kh + ((size_t)c * SEQ + u * 64 + lane) * 8, &Ks[0][idx * 512]);
        GLOBAL_LOAD_LDS16(vh + ((size_t)(u * 8 + c) * HDIM + lane) * 8, &Vts[0][idx * 512]);
    }
    __syncthreads();

    for (int kt = 0; kt < SEQ / 128; ++kt) {
        const int cur = kt & 1;

        // stage tile kt+1 into the other buffer
        if (kt + 1 < SEQ / 128) {
            #pragma unroll
            for (int j = 0; j < 2; ++j) {
                const int idx = sidx0 + j;
                const int u = idx >> 3, c = idx & 7;
                GLOBAL_LOAD_LDS16(kh + ((size_t)c * SEQ + (kt + 1) * 128 + u * 64 + lane) * 8,
                                  &Ks[cur ^ 1][idx * 512]);
                GLOBAL_LOAD_LDS16(vh + ((size_t)((kt + 1) * 16 + u * 8 + c) * HDIM + lane) * 8,
                                  &Vts[cur ^ 1][idx * 512]);
            }
        }

        // ---- two 64-key subtiles ----
        #pragma unroll
        for (int u = 0; u < 2; ++u) {
            const _Float16* ksub = &Ks[cur][u * 4096];
            const _Float16* vsub = &Vts[cur][u * 4096];

            // QK^T: S^T tiles (keytile 0: keys 0-31, keytile 1: keys 32-63)
            f32x16 s0 = {}, s1 = {};
            __builtin_amdgcn_s_setprio(1);
            #pragma unroll
            for (int kk = 0; kk < 4; ++kk) {
                const f16x8 k0 = *(const f16x8*)&ksub[(kk * 2 + hi) * 512 + l31 * 8];
                const f16x8 k1 = *(const f16x8*)&ksub[(kk * 2 + hi) * 512 + (32 + l31) * 8];
                s0 = __builtin_amdgcn_mfma_f32_32x32x16_f16(k0, qf[kk], s0, 0, 0, 0);
                s1 = __builtin_amdgcn_mfma_f32_32x32x16_f16(k1, qf[kk], s1, 0, 0, 0);
            }
            __builtin_amdgcn_s_setprio(0);

            // exp2 + in-register transpose to PV A-frags
            f16x8 pa[4];
            softmax_frag(s0, s1, rs, pa);

            // PV: O[q][d] += P[q][k] V[k][d], 4 ksteps of 16 keys
            __builtin_amdgcn_s_setprio(1);
            #pragma unroll
            for (int ks = 0; ks < 4; ++ks) {
                const f16x8 v0 = *(const f16x8*)&vsub[(ks * 2 + hi) * 512 + l31 * 8];
                const f16x8 v1 = *(const f16x8*)&vsub[(ks * 2 + hi) * 512 + (32 + l31) * 8];
                acc0 = __builtin_amdgcn_mfma_f32_32x32x16_f16(pa[ks], v0, acc0, 0, 0, 0);
                acc1 = __builtin_amdgcn_mfma_f32_32x32x16_f16(pa[ks], v1, acc1, 0, 0, 0);
            }
            __builtin_amdgcn_s_setprio(0);
        }

        __syncthreads();
    }

    // lane covers half the keys for q=l31; partner lane^32 has the complement
    rs += __shfl_xor(rs, 32);
    const float inv = 1.f / rs;

    #pragma unroll
    for (int r = 0; r < 16; ++r) {
        const int qo = (r & 3) + 8 * (r >> 2) + 4 * hi;     // wave-local q row
        const float invr = __shfl(inv, qo);                  // lane qo holds inv for q=qo
        const int row = b * SEQ + q0 + wave * 32 + qo;
        val[(size_t)row * D_MODEL + h * HDIM + l31]      = (_Float16)(acc0[r] * invr);
        val[(size_t)row * D_MODEL + h * HDIM + 32 + l31] = (_Float16)(acc1[r] * invr);
    }
}

extern "C" void kernel_launch(void* const* d_in, const int* in_sizes, int n_in,
                              void* d_out, int out_size, void* d_ws, size_t ws_size,
                              hipStream_t stream)
{
    const float* x     = (const float*)d_in[0];
    const float* W_qkv = (const float*)d_in[1];
    const float* b_qkv = (const float*)d_in[2];
    const float* W_out = (const float*)d_in[3];
    const float* b_out = (const float*)d_in[4];

    char* ws = (char*)d_ws;
    _Float16* Ksw   = (_Float16*)ws;                      // [32][8][2048][8]  8 MiB
    _Float16* val_h = (_Float16*)(ws + (8u << 20));       // [4096][1024]      8 MiB
    _Float16* wq_t  = (_Float16*)(ws + (16u << 20));      // [3072][1024]      6 MiB
    _Float16* wo_t  = (_Float16*)(ws + (22u << 20));      // [1024][1024]      2 MiB
    _Float16* qkv_h = (_Float16*)(ws + (24u << 20));      // [4096][3072]     24 MiB
    _Float16* x_h   = (_Float16*)(ws + (48u << 20));      // [4096][1024]      8 MiB
    _Float16* Vsw   = (_Float16*)(ws + (48u << 20));      // overwrites dead x_h

    prep_kernel<<<5120, 256, 0, stream>>>(x, x_h, W_qkv, wq_t, W_out, wo_t);
    gemm_qkv_kernel<<<dim3(3 * D_MODEL / 128, NTOK / 128), 512, 0, stream>>>(
        x_h, wq_t, b_qkv, qkv_h, NTOK, 3 * D_MODEL, D_MODEL);
    swizzle_kv_kernel<<<dim3(SEQ / 64, NHEAD, BATCH), 256, 0, stream>>>(qkv_h, Ksw, Vsw);
    attn_mfma_kernel<<<dim3(256, 1, 1), 512, 0, stream>>>(qkv_h, Ksw, Vsw, val_h);
    gemm_out_kernel<<<dim3(D_MODEL / 64, NTOK / 128), 512, 0, stream>>>(
        val_h, wo_t, b_out, (float*)d_out);
}

// Round 7
// 211.485 us; speedup vs baseline: 1.0539x; 1.0252x over previous
//
#include <hip/hip_runtime.h>

// MultiHeadSelfAttention  B=2 S=2048 D=1024 H=16 d=64, fp32 in/out.
// R15: GEMM1 gets the real counted-vmcnt pipeline (T3+T4): 3 LDS buffers,
//      prefetch 2 K-tiles ahead, raw s_barrier + asm s_waitcnt vmcnt(4)
//      (never 0 in main loop; tail peeled vmcnt(2)/vmcnt(0)), setprio around
//      the MFMA cluster, sched_barrier(0) fences against rule-18 hoisting.
//   Why: R14's __syncthreads dbuf was a no-op (compiler drains vmcnt(0) at
//   every barrier -> prefetch never spans a barrier; == learn_hip m99/m100).
//   Counted vmcnt gives loads 2 full K-step periods to land.
// GEMM2/attn/prep/swizzle unchanged from R14.
// ws: Ksw 8M @0 | val_h 8M @8M | wq_t 6M @16M | wo_t 2M @22M | qkv 24M @24M
//     | x_h 8M @48M (dead after GEMM1, overwritten by Vsw)

#define D_MODEL 1024
#define NHEAD   16
#define HDIM    64
#define SEQ     2048
#define BATCH   2
#define NTOK    (BATCH * SEQ)

typedef float    f32x4  __attribute__((ext_vector_type(4)));
typedef float    f32x16 __attribute__((ext_vector_type(16)));
typedef _Float16 f16x8  __attribute__((ext_vector_type(8)));
typedef _Float16 f16x4  __attribute__((ext_vector_type(4)));

#define GLOBAL_LOAD_LDS16(gptr, lptr)                                            \
    __builtin_amdgcn_global_load_lds(                                            \
        (const __attribute__((address_space(1))) unsigned int*)(gptr),           \
        (__attribute__((address_space(3))) unsigned int*)(lptr), 16, 0, 0)

// ---------------- prep: x->fp16, W_qkv^T, W_out^T (one launch) ----------------
__global__ __launch_bounds__(256) void prep_kernel(
    const float* __restrict__ x, _Float16* __restrict__ xh,
    const float* __restrict__ Wqkv, _Float16* __restrict__ wq_t,
    const float* __restrict__ Wout, _Float16* __restrict__ wo_t)
{
    const int bx = blockIdx.x;
    const int tid = threadIdx.x;
    if (bx < 4096) {
        const int i = (bx * 256 + tid) * 4;
        const float4 v = *(const float4*)&x[i];
        f16x4 hh;
        hh[0] = (_Float16)v.x; hh[1] = (_Float16)v.y;
        hh[2] = (_Float16)v.z; hh[3] = (_Float16)v.w;
        *(f16x4*)&xh[i] = hh;
        return;
    }
    __shared__ float ts[64][65];
    const float* W; _Float16* Wt; int N, n0, k0;
    if (bx < 4096 + 768) {
        const int local = bx - 4096;
        W = Wqkv; Wt = wq_t; N = 3072;
        n0 = (local % 48) * 64; k0 = (local / 48) * 64;
    } else {
        const int local = bx - 4864;
        W = Wout; Wt = wo_t; N = 1024;
        n0 = (local % 16) * 64; k0 = (local / 16) * 64;
    }
    {
        const int r = tid >> 2, c = (tid & 3) << 4;
        const float* src = W + (size_t)(k0 + r) * N + n0 + c;
        #pragma unroll
        for (int u = 0; u < 4; ++u)
            *(float4*)&ts[r][c + u * 4] = *(const float4*)&src[u * 4];
    }
    __syncthreads();
    {
        const int n = tid >> 2, kg = (tid & 3) << 4;
        f16x8 v0, v1;
        #pragma unroll
        for (int j = 0; j < 8; ++j) {
            v0[j] = (_Float16)ts[kg + j][n];
            v1[j] = (_Float16)ts[kg + 8 + j][n];
        }
        _Float16* dst = Wt + (size_t)(n0 + n) * D_MODEL + k0 + kg;
        *(f16x8*)&dst[0] = v0;
        *(f16x8*)&dst[8] = v1;
    }
}

// ---------------- GEMM1: 128x128 tile, BK=32, 512 threads (8 waves of 32x64),
//   3-buffer counted-vmcnt pipeline: stage t+2, gate vmcnt(4), raw barriers ---
__global__ __launch_bounds__(512) void gemm_qkv_kernel(
    const _Float16* __restrict__ A, const _Float16* __restrict__ Bt,
    const float* __restrict__ bias, _Float16* __restrict__ Cout,
    int M, int N, int K)
{
    __shared__ _Float16 lds[3][2][4096];  // [buf3][plane A/B][chunk4][row128][8] 48KB
    const int tid = threadIdx.x;
    const int wave = tid >> 6, lane = tid & 63;
    const int quad = lane >> 4, l16 = lane & 15;
    const int m0 = blockIdx.y * 128, n0 = blockIdx.x * 128;
    const int wr = wave >> 1, wc = wave & 1;       // wave tile: rows wr*32, cols wc*64

    f32x4 acc[2][4] = {};

    const bool isA = wave < 4;
    const _Float16* gsrc = isA ? (A + (size_t)m0 * K) : (Bt + (size_t)n0 * K);
    const int plane = isA ? 0 : 1;
    const int sbase = (wave & 3) * 2;              // 2 segments of 1KB per wave

#define G1_STAGE(tt, bi) {                                                     \
        const int _k1 = (tt) * 32;                                             \
        _Pragma("unroll")                                                      \
        for (int _j = 0; _j < 2; ++_j) {                                       \
            const int _seg = sbase + _j;                                       \
            const int _row = ((_seg & 1) << 6) | lane;                         \
            GLOBAL_LOAD_LDS16(gsrc + (size_t)_row * K + _k1 + (_seg >> 1) * 8, \
                              &lds[bi][plane][_seg * 512]);                    \
        } }

#define G1_COMPUTE(bi) {                                                       \
        f16x8 a[2], b[4];                                                      \
        _Pragma("unroll")                                                      \
        for (int mt = 0; mt < 2; ++mt)                                         \
            a[mt] = *(const f16x8*)&lds[bi][0][quad * 1024 + (wr * 32 + mt * 16 + l16) * 8]; \
        _Pragma("unroll")                                                      \
        for (int nt = 0; nt < 4; ++nt)                                         \
            b[nt] = *(const f16x8*)&lds[bi][1][quad * 1024 + (wc * 64 + nt * 16 + l16) * 8]; \
        __builtin_amdgcn_s_setprio(1);                                         \
        _Pragma("unroll")                                                      \
        for (int mt = 0; mt < 2; ++mt)                                         \
            _Pragma("unroll")                                                  \
            for (int nt = 0; nt < 4; ++nt)                                     \
                acc[mt][nt] = __builtin_amdgcn_mfma_f32_16x16x32_f16(a[mt], b[nt], acc[mt][nt], 0, 0, 0); \
        __builtin_amdgcn_s_setprio(0); }

// one K-step: stage t+2 | gate own tile-t loads | barrier | compute | barrier
// sched_barrier(0) fences: (1) after barrier-1 so ds_reads can't hoist above,
// (2) before barrier-2 so reads+lgkm waits can't sink below (rule-18 race:
// buf[cur] is overwritten by stage at iter t+1), (3) after barrier-2 so next
// iter's stage can't hoist into this iter.
#define G1_KSTEP(t, gatestr) {                                                 \
        const int _cur = (t) % 3;                                              \
        if ((t) + 2 < nk) { G1_STAGE((t) + 2, ((t) + 2) % 3); }                \
        asm volatile("s_waitcnt " gatestr ::: "memory");                       \
        __builtin_amdgcn_s_barrier();                                          \
        __builtin_amdgcn_sched_barrier(0);                                     \
        G1_COMPUTE(_cur);                                                      \
        __builtin_amdgcn_sched_barrier(0);                                     \
        __builtin_amdgcn_s_barrier();                                          \
        __builtin_amdgcn_sched_barrier(0);                                     \
    }

    const int nk = K / 32;                 // 32
    G1_STAGE(0, 0);
    G1_STAGE(1, 1);

    for (int t = 0; t < nk - 2; ++t)
        G1_KSTEP(t, "vmcnt(4)");
    G1_KSTEP(nk - 2, "vmcnt(2)");
    G1_KSTEP(nk - 1, "vmcnt(0)");

#undef G1_KSTEP
#undef G1_COMPUTE
#undef G1_STAGE

    #pragma unroll
    for (int nt = 0; nt < 4; ++nt) {
        const int col = n0 + wc * 64 + nt * 16 + l16;
        const float bv = bias[col];
        #pragma unroll
        for (int mt = 0; mt < 2; ++mt) {
            #pragma unroll
            for (int r = 0; r < 4; ++r) {
                const int row = m0 + wr * 32 + mt * 16 + quad * 4 + r;
                Cout[(size_t)row * N + col] = (_Float16)(acc[mt][nt][r] + bv);
            }
        }
    }
}

// ---------------- GEMM2: 128x64 tile, BK=32, 512 threads (8 waves of 32x32),
//                  double-buffered staging, one barrier per K-step, fp32 out --
__global__ __launch_bounds__(512) void gemm_out_kernel(
    const _Float16* __restrict__ A, const _Float16* __restrict__ Bt,
    const float* __restrict__ bias, float* __restrict__ Cout)
{
    const int K = D_MODEL, N = D_MODEL;
    __shared__ _Float16 ldsA[2][4096];    // [buf][chunk4][row128][8] 8KB x2
    __shared__ _Float16 ldsB[2][2048];    // [buf][chunk4][row64][8]  4KB x2
    const int tid = threadIdx.x;
    const int wave = tid >> 6, lane = tid & 63;
    const int quad = lane >> 4, l16 = lane & 15;
    const int m0 = blockIdx.y * 128, n0 = blockIdx.x * 64;
    const int wr = wave >> 1, wc = wave & 1;       // wave tile: rows wr*32, cols wc*32

    f32x4 acc[2][2] = {};

    // prologue: stage K-tile 0 into buf 0
    if (wave < 4) {
        #pragma unroll
        for (int j = 0; j < 2; ++j) {
            const int seg = wave * 2 + j;
            const int chunk = seg >> 1;
            const int row = ((seg & 1) << 6) | lane;
            GLOBAL_LOAD_LDS16(A + (size_t)(m0 + row) * K + chunk * 8, &ldsA[0][seg * 512]);
        }
    } else {
        const int seg = wave - 4;
        GLOBAL_LOAD_LDS16(Bt + (size_t)(n0 + lane) * K + seg * 8, &ldsB[0][seg * 512]);
    }
    __syncthreads();

    const int nk = K / 32;
    for (int t = 0; t < nk; ++t) {
        const int cur = t & 1;

        if (t + 1 < nk) {
            const int k1 = (t + 1) * 32;
            if (wave < 4) {
                #pragma unroll
                for (int j = 0; j < 2; ++j) {
                    const int seg = wave * 2 + j;
                    const int chunk = seg >> 1;
                    const int row = ((seg & 1) << 6) | lane;
                    GLOBAL_LOAD_LDS16(A + (size_t)(m0 + row) * K + k1 + chunk * 8,
                                      &ldsA[cur ^ 1][seg * 512]);
                }
            } else {
                const int seg = wave - 4;
                GLOBAL_LOAD_LDS16(Bt + (size_t)(n0 + lane) * K + k1 + seg * 8,
                                  &ldsB[cur ^ 1][seg * 512]);
            }
        }

        f16x8 a[2], b[2];
        #pragma unroll
        for (int mt = 0; mt < 2; ++mt)
            a[mt] = *(const f16x8*)&ldsA[cur][quad * 1024 + (wr * 32 + mt * 16 + l16) * 8];
        #pragma unroll
        for (int nt = 0; nt < 2; ++nt)
            b[nt] = *(const f16x8*)&ldsB[cur][quad * 512 + (wc * 32 + nt * 16 + l16) * 8];
        #pragma unroll
        for (int mt = 0; mt < 2; ++mt)
            #pragma unroll
            for (int nt = 0; nt < 2; ++nt)
                acc[mt][nt] = __builtin_amdgcn_mfma_f32_16x16x32_f16(a[mt], b[nt], acc[mt][nt], 0, 0, 0);

        __syncthreads();
    }

    #pragma unroll
    for (int nt = 0; nt < 2; ++nt) {
        const int col = n0 + wc * 32 + nt * 16 + l16;
        const float bv = bias[col];
        #pragma unroll
        for (int mt = 0; mt < 2; ++mt) {
            #pragma unroll
            for (int r = 0; r < 4; ++r) {
                const int row = m0 + wr * 32 + mt * 16 + quad * 4 + r;
                Cout[(size_t)row * N + col] = acc[mt][nt][r] + bv;
            }
        }
    }
}

// ---------------- K,V slices of qkv -> swizzled MFMA-ready layouts ----------------
__global__ __launch_bounds__(256) void swizzle_kv_kernel(
    const _Float16* __restrict__ qkv,
    _Float16* __restrict__ Ksw, _Float16* __restrict__ Vsw)
{
    __shared__ _Float16 ts[64][72];
    const int tid = threadIdx.x;
    const int s0 = blockIdx.x * 64, h = blockIdx.y, b = blockIdx.z;
    const size_t hsz = (size_t)8 * SEQ * 8;
    _Float16* kh = Ksw + (size_t)(b * NHEAD + h) * hsz;
    _Float16* vh = Vsw + (size_t)(b * NHEAD + h) * hsz;

    {
        const int s = s0 + (tid >> 2);
        const int dg = (tid & 3) << 4;
        const _Float16* src = qkv + (size_t)(b * SEQ + s) * (3 * D_MODEL) + h * (3 * HDIM) + HDIM + dg;
        const f16x8 v0 = *(const f16x8*)&src[0];
        const f16x8 v1 = *(const f16x8*)&src[8];
        const int c0 = dg >> 3;
        *(f16x8*)&kh[((size_t)c0 * SEQ + s) * 8]       = v0;
        *(f16x8*)&kh[((size_t)(c0 + 1) * SEQ + s) * 8] = v1;
    }
    {
        const int s = tid >> 2, dg = (tid & 3) << 4;
        const _Float16* src = qkv + (size_t)(b * SEQ + s0 + s) * (3 * D_MODEL) + h * (3 * HDIM) + 2 * HDIM + dg;
        *(f16x8*)&ts[s][dg]     = *(const f16x8*)&src[0];
        *(f16x8*)&ts[s][dg + 8] = *(const f16x8*)&src[8];
    }
    __syncthreads();
    {
        const int d = tid >> 2, sg = (tid & 3) << 4;
        f16x8 v0, v1;
        #pragma unroll
        for (int j = 0; j < 8; ++j) { v0[j] = ts[sg + j][d]; v1[j] = ts[sg + 8 + j][d]; }
        const int cs0 = (s0 + sg) >> 3;
        *(f16x8*)&vh[((size_t)cs0 * HDIM + d) * 8]       = v0;
        *(f16x8*)&vh[((size_t)(cs0 + 1) * HDIM + d) * 8] = v1;
    }
}

// softmax fragment: s0/s1 (keys 0-31 / 32-63 scores for q=l31) -> 4 PV A-frags
// pa[ks][j] = P[q=l31][key = ks*16 + hi*8 + j], rs += sum of own 32 exp2's.
__device__ __forceinline__ void softmax_frag(
    const f32x16 s0, const f32x16 s1, float& rs, f16x8 pa[4])
{
    #pragma unroll
    for (int half = 0; half < 2; ++half) {
        const f32x16 sv = half ? s1 : s0;
        float p[16];
        #pragma unroll
        for (int r = 0; r < 16; ++r)
            p[r] = __builtin_amdgcn_exp2f(sv[r]);
        #pragma unroll
        for (int r = 0; r < 16; r += 4)
            rs += (p[r] + p[r + 1]) + (p[r + 2] + p[r + 3]);

        union { f16x8 hv; unsigned u[4]; } lo, hh;
        {
            const unsigned A = __builtin_bit_cast(unsigned, __builtin_amdgcn_cvt_pkrtz(p[0], p[1]));
            const unsigned B = __builtin_bit_cast(unsigned, __builtin_amdgcn_cvt_pkrtz(p[2], p[3]));
            const unsigned C = __builtin_bit_cast(unsigned, __builtin_amdgcn_cvt_pkrtz(p[4], p[5]));
            const unsigned D = __builtin_bit_cast(unsigned, __builtin_amdgcn_cvt_pkrtz(p[6], p[7]));
            const auto rac = __builtin_amdgcn_permlane32_swap(A, C, false, false);
            const auto rbd = __builtin_amdgcn_permlane32_swap(B, D, false, false);
            lo.u[0] = rac[0]; lo.u[1] = rbd[0]; lo.u[2] = rac[1]; lo.u[3] = rbd[1];
        }
        {
            const unsigned E = __builtin_bit_cast(unsigned, __builtin_amdgcn_cvt_pkrtz(p[8],  p[9]));
            const unsigned F = __builtin_bit_cast(unsigned, __builtin_amdgcn_cvt_pkrtz(p[10], p[11]));
            const unsigned G = __builtin_bit_cast(unsigned, __builtin_amdgcn_cvt_pkrtz(p[12], p[13]));
            const unsigned H = __builtin_bit_cast(unsigned, __builtin_amdgcn_cvt_pkrtz(p[14], p[15]));
            const auto reg = __builtin_amdgcn_permlane32_swap(E, G, false, false);
            const auto rfh = __builtin_amdgcn_permlane32_swap(F, H, false, false);
            hh.u[0] = reg[0]; hh.u[1] = rfh[0]; hh.u[2] = reg[1]; hh.u[3] = rfh[1];
        }
        pa[half * 2]     = lo.hv;
        pa[half * 2 + 1] = hh.hv;
    }
}

// ---------------- fp16 MFMA flash attention, 32x32, QBLK=256 (8 waves x 32q),
//                  KVBLK=128 (2x 64-key subtiles per barrier), dbuf K/V --------
__global__ __launch_bounds__(512) void attn_mfma_kernel(
    const _Float16* __restrict__ qkv,
    const _Float16* __restrict__ Ksw, const _Float16* __restrict__ Vsw,
    _Float16* __restrict__ val)
{
    __shared__ _Float16 Ks[2][8192];      // [sub2][dchunk8][key64][8]  16KB x2
    __shared__ _Float16 Vts[2][8192];     // [sub2][kchunk8][d64][8]    16KB x2

    const int tid = threadIdx.x;
    const int wave = tid >> 6, lane = tid & 63;
    const int l31 = lane & 31, hi = lane >> 5;

    // XCD-chunked swizzle: 256 blocks, 32/XCD = 4 heads x 8 qt -> K/V 2MB/XCD
    const int id = blockIdx.x;
    const int g  = (id & 7) * 32 + (id >> 3);
    const int qt = g & 7, hb = g >> 3;
    const int h  = hb & 15, b = hb >> 4;
    const int q0 = qt * 256;

    const size_t hsz = (size_t)8 * SEQ * 8;
    const _Float16* kh = Ksw + (size_t)(b * NHEAD + h) * hsz;
    const _Float16* vh = Vsw + (size_t)(b * NHEAD + h) * hsz;

    // Q B-fragments: col=l31 -> q row, k = kk*16 + hi*8 + j
    f16x8 qf[4];
    {
        const int row = q0 + wave * 32 + l31;
        const _Float16* src = qkv + (size_t)(b * SEQ + row) * (3 * D_MODEL) + h * (3 * HDIM) + hi * 8;
        #pragma unroll
        for (int kk = 0; kk < 4; ++kk) {
            const f16x8 t = *(const f16x8*)(src + kk * 16);
            #pragma unroll
            for (int j = 0; j < 8; ++j)
                qf[kk][j] = (_Float16)((float)t[j] * 0.1803368802f);   // (1/8)*log2(e)
        }
    }

    f32x16 acc0 = {};      // O[q][d], dtile 0 (d = l31)
    f32x16 acc1 = {};      // dtile 1 (d = 32+l31)
    float rs = 0.f;

    // staging: 8 waves x 2 chunk-instrs each cover sub(2) x chunk(8) for K and V
    const int sidx0 = wave * 2;            // 0..14 even
    // prologue: stage 128-key tile 0 into buffer 0
    #pragma unroll
    for (int j = 0; j < 2; ++j) {
        const int idx = sidx0 + j;         // 0..15
        const int u = idx >> 3, c = idx & 7;
        GLOBAL_LOAD_LDS16(kh + ((size_t)c * SEQ + u * 64 + lane) * 8, &Ks[0][idx * 512]);
        GLOBAL_LOAD_LDS16(vh + ((size_t)(u * 8 + c) * HDIM + lane) * 8, &Vts[0][idx * 512]);
    }
    __syncthreads();

    for (int kt = 0; kt < SEQ / 128; ++kt) {
        const int cur = kt & 1;

        // stage tile kt+1 into the other buffer
        if (kt + 1 < SEQ / 128) {
            #pragma unroll
            for (int j = 0; j < 2; ++j) {
                const int idx = sidx0 + j;
                const int u = idx >> 3, c = idx & 7;
                GLOBAL_LOAD_LDS16(kh + ((size_t)c * SEQ + (kt + 1) * 128 + u * 64 + lane) * 8,
                                  &Ks[cur ^ 1][idx * 512]);
                GLOBAL_LOAD_LDS16(vh + ((size_t)((kt + 1) * 16 + u * 8 + c) * HDIM + lane) * 8,
                                  &Vts[cur ^ 1][idx * 512]);
            }
        }

        // ---- two 64-key subtiles ----
        #pragma unroll
        for (int u = 0; u < 2; ++u) {
            const _Float16* ksub = &Ks[cur][u * 4096];
            const _Float16* vsub = &Vts[cur][u * 4096];

            // QK^T: S^T tiles (keytile 0: keys 0-31, keytile 1: keys 32-63)
            f32x16 s0 = {}, s1 = {};
            __builtin_amdgcn_s_setprio(1);
            #pragma unroll
            for (int kk = 0; kk < 4; ++kk) {
                const f16x8 k0 = *(const f16x8*)&ksub[(kk * 2 + hi) * 512 + l31 * 8];
                const f16x8 k1 = *(const f16x8*)&ksub[(kk * 2 + hi) * 512 + (32 + l31) * 8];
                s0 = __builtin_amdgcn_mfma_f32_32x32x16_f16(k0, qf[kk], s0, 0, 0, 0);
                s1 = __builtin_amdgcn_mfma_f32_32x32x16_f16(k1, qf[kk], s1, 0, 0, 0);
            }
            __builtin_amdgcn_s_setprio(0);

            // exp2 + in-register transpose to PV A-frags
            f16x8 pa[4];
            softmax_frag(s0, s1, rs, pa);

            // PV: O[q][d] += P[q][k] V[k][d], 4 ksteps of 16 keys
            __builtin_amdgcn_s_setprio(1);
            #pragma unroll
            for (int ks = 0; ks < 4; ++ks) {
                const f16x8 v0 = *(const f16x8*)&vsub[(ks * 2 + hi) * 512 + l31 * 8];
                const f16x8 v1 = *(const f16x8*)&vsub[(ks * 2 + hi) * 512 + (32 + l31) * 8];
                acc0 = __builtin_amdgcn_mfma_f32_32x32x16_f16(pa[ks], v0, acc0, 0, 0, 0);
                acc1 = __builtin_amdgcn_mfma_f32_32x32x16_f16(pa[ks], v1, acc1, 0, 0, 0);
            }
            __builtin_amdgcn_s_setprio(0);
        }

        __syncthreads();
    }

    // lane covers half the keys for q=l31; partner lane^32 has the complement
    rs += __shfl_xor(rs, 32);
    const float inv = 1.f / rs;

    #pragma unroll
    for (int r = 0; r < 16; ++r) {
        const int qo = (r & 3) + 8 * (r >> 2) + 4 * hi;     // wave-local q row
        const float invr = __shfl(inv, qo);                  // lane qo holds inv for q=qo
        const int row = b * SEQ + q0 + wave * 32 + qo;
        val[(size_t)row * D_MODEL + h * HDIM + l31]      = (_Float16)(acc0[r] * invr);
        val[(size_t)row * D_MODEL + h * HDIM + 32 + l31] = (_Float16)(acc1[r] * invr);
    }
}

extern "C" void kernel_launch(void* const* d_in, const int* in_sizes, int n_in,
                              void* d_out, int out_size, void* d_ws, size_t ws_size,
                              hipStream_t stream)
{
    const float* x     = (const float*)d_in[0];
    const float* W_qkv = (const float*)d_in[1];
    const float* b_qkv = (const float*)d_in[2];
    const float* W_out = (const float*)d_in[3];
    const float* b_out = (const float*)d_in[4];

    char* ws = (char*)d_ws;
    _Float16* Ksw   = (_Float16*)ws;                      // [32][8][2048][8]  8 MiB
    _Float16* val_h = (_Float16*)(ws + (8u << 20));       // [4096][1024]      8 MiB
    _Float16* wq_t  = (_Float16*)(ws + (16u << 20));      // [3072][1024]      6 MiB
    _Float16* wo_t  = (_Float16*)(ws + (22u << 20));      // [1024][1024]      2 MiB
    _Float16* qkv_h = (_Float16*)(ws + (24u << 20));      // [4096][3072]     24 MiB
    _Float16* x_h   = (_Float16*)(ws + (48u << 20));      // [4096][1024]      8 MiB
    _Float16* Vsw   = (_Float16*)(ws + (48u << 20));      // overwrites dead x_h

    prep_kernel<<<5120, 256, 0, stream>>>(x, x_h, W_qkv, wq_t, W_out, wo_t);
    gemm_qkv_kernel<<<dim3(3 * D_MODEL / 128, NTOK / 128), 512, 0, stream>>>(
        x_h, wq_t, b_qkv, qkv_h, NTOK, 3 * D_MODEL, D_MODEL);
    swizzle_kv_kernel<<<dim3(SEQ / 64, NHEAD, BATCH), 256, 0, stream>>>(qkv_h, Ksw, Vsw);
    attn_mfma_kernel<<<dim3(256, 1, 1), 512, 0, stream>>>(qkv_h, Ksw, Vsw, val_h);
    gemm_out_kernel<<<dim3(D_MODEL / 64, NTOK / 128), 512, 0, stream>>>(
        val_h, wo_t, b_out, (float*)d_out);
}

// Round 9
// 202.841 us; speedup vs baseline: 1.0988x; 1.0426x over previous
//
#include <hip/hip_runtime.h>

// MultiHeadSelfAttention  B=2 S=2048 D=1024 H=16 d=64, fp32 in/out.
// R16b: resubmit of R16 (bench infra failed twice; no kernel verdict).
// R16: swizzle_kv kernel DELETED -- GEMM1's epilogue writes Q/K/V directly:
//      each wave's 64-col region is wholly Q, K, or V of one head (64-aligned
//      mod 192 -> wave-uniform branch). Q -> compact q_h[4096][1024];
//      K -> Ksw scalar stores (same formula as old swizzle); V -> Vsw via
//      aligned f16x4 stores (4 acc rows = 4 consecutive s in an 8-block).
//      Saves: 1 launch, 16MB qkv K/V write + 16MB swizzle read; ws 56->48MB.
//   Why: R15 counted-vmcnt gave only +5% (regime-gate: needs full 8-phase);
//   pre-committed pivot to kernel-count/traffic reduction.
// GEMM1 K-loop = R15 (3-buf counted vmcnt). GEMM2/attn-core/prep unchanged
// (attn Q read re-pointed to q_h, stride 1024).
// ws: Ksw 8M @0 | val_h 8M @8 | wq_t 6M @16 | wo_t 2M @22 | q_h 8M @24
//     | x_h 8M @32 | Vsw 8M @40   (total 48M, no aliasing)

#define D_MODEL 1024
#define NHEAD   16
#define HDIM    64
#define SEQ     2048
#define BATCH   2
#define NTOK    (BATCH * SEQ)

typedef float    f32x4  __attribute__((ext_vector_type(4)));
typedef float    f32x16 __attribute__((ext_vector_type(16)));
typedef _Float16 f16x8  __attribute__((ext_vector_type(8)));
typedef _Float16 f16x4  __attribute__((ext_vector_type(4)));

#define GLOBAL_LOAD_LDS16(gptr, lptr)                                            \
    __builtin_amdgcn_global_load_lds(                                            \
        (const __attribute__((address_space(1))) unsigned int*)(gptr),           \
        (__attribute__((address_space(3))) unsigned int*)(lptr), 16, 0, 0)

// ---------------- prep: x->fp16, W_qkv^T, W_out^T (one launch) ----------------
__global__ __launch_bounds__(256) void prep_kernel(
    const float* __restrict__ x, _Float16* __restrict__ xh,
    const float* __restrict__ Wqkv, _Float16* __restrict__ wq_t,
    const float* __restrict__ Wout, _Float16* __restrict__ wo_t)
{
    const int bx = blockIdx.x;
    const int tid = threadIdx.x;
    if (bx < 4096) {
        const int i = (bx * 256 + tid) * 4;
        const float4 v = *(const float4*)&x[i];
        f16x4 hh;
        hh[0] = (_Float16)v.x; hh[1] = (_Float16)v.y;
        hh[2] = (_Float16)v.z; hh[3] = (_Float16)v.w;
        *(f16x4*)&xh[i] = hh;
        return;
    }
    __shared__ float ts[64][65];
    const float* W; _Float16* Wt; int N, n0, k0;
    if (bx < 4096 + 768) {
        const int local = bx - 4096;
        W = Wqkv; Wt = wq_t; N = 3072;
        n0 = (local % 48) * 64; k0 = (local / 48) * 64;
    } else {
        const int local = bx - 4864;
        W = Wout; Wt = wo_t; N = 1024;
        n0 = (local % 16) * 64; k0 = (local / 16) * 64;
    }
    {
        const int r = tid >> 2, c = (tid & 3) << 4;
        const float* src = W + (size_t)(k0 + r) * N + n0 + c;
        #pragma unroll
        for (int u = 0; u < 4; ++u)
            *(float4*)&ts[r][c + u * 4] = *(const float4*)&src[u * 4];
    }
    __syncthreads();
    {
        const int n = tid >> 2, kg = (tid & 3) << 4;
        f16x8 v0, v1;
        #pragma unroll
        for (int j = 0; j < 8; ++j) {
            v0[j] = (_Float16)ts[kg + j][n];
            v1[j] = (_Float16)ts[kg + 8 + j][n];
        }
        _Float16* dst = Wt + (size_t)(n0 + n) * D_MODEL + k0 + kg;
        *(f16x8*)&dst[0] = v0;
        *(f16x8*)&dst[8] = v1;
    }
}

// ---------------- GEMM1: 128x128 tile, BK=32, 512 threads (8 waves of 32x64),
//   3-buffer counted-vmcnt pipeline; epilogue scatters Q/K/V to final layouts -
__global__ __launch_bounds__(512) void gemm_qkv_kernel(
    const _Float16* __restrict__ A, const _Float16* __restrict__ Bt,
    const float* __restrict__ bias, _Float16* __restrict__ Qh,
    _Float16* __restrict__ Ksw, _Float16* __restrict__ Vsw,
    int M, int N, int K)
{
    __shared__ _Float16 lds[3][2][4096];  // [buf3][plane A/B][chunk4][row128][8] 48KB
    const int tid = threadIdx.x;
    const int wave = tid >> 6, lane = tid & 63;
    const int quad = lane >> 4, l16 = lane & 15;
    const int m0 = blockIdx.y * 128, n0 = blockIdx.x * 128;
    const int wr = wave >> 1, wc = wave & 1;       // wave tile: rows wr*32, cols wc*64

    f32x4 acc[2][4] = {};

    const bool isA = wave < 4;
    const _Float16* gsrc = isA ? (A + (size_t)m0 * K) : (Bt + (size_t)n0 * K);
    const int plane = isA ? 0 : 1;
    const int sbase = (wave & 3) * 2;              // 2 segments of 1KB per wave

#define G1_STAGE(tt, bi) {                                                     \
        const int _k1 = (tt) * 32;                                             \
        _Pragma("unroll")                                                      \
        for (int _j = 0; _j < 2; ++_j) {                                       \
            const int _seg = sbase + _j;                                       \
            const int _row = ((_seg & 1) << 6) | lane;                         \
            GLOBAL_LOAD_LDS16(gsrc + (size_t)_row * K + _k1 + (_seg >> 1) * 8, \
                              &lds[bi][plane][_seg * 512]);                    \
        } }

#define G1_COMPUTE(bi) {                                                       \
        f16x8 a[2], b[4];                                                      \
        _Pragma("unroll")                                                      \
        for (int mt = 0; mt < 2; ++mt)                                         \
            a[mt] = *(const f16x8*)&lds[bi][0][quad * 1024 + (wr * 32 + mt * 16 + l16) * 8]; \
        _Pragma("unroll")                                                      \
        for (int nt = 0; nt < 4; ++nt)                                         \
            b[nt] = *(const f16x8*)&lds[bi][1][quad * 1024 + (wc * 64 + nt * 16 + l16) * 8]; \
        __builtin_amdgcn_s_setprio(1);                                         \
        _Pragma("unroll")                                                      \
        for (int mt = 0; mt < 2; ++mt)                                         \
            _Pragma("unroll")                                                  \
            for (int nt = 0; nt < 4; ++nt)                                     \
                acc[mt][nt] = __builtin_amdgcn_mfma_f32_16x16x32_f16(a[mt], b[nt], acc[mt][nt], 0, 0, 0); \
        __builtin_amdgcn_s_setprio(0); }

#define G1_KSTEP(t, gatestr) {                                                 \
        const int _cur = (t) % 3;                                              \
        if ((t) + 2 < nk) { G1_STAGE((t) + 2, ((t) + 2) % 3); }                \
        asm volatile("s_waitcnt " gatestr ::: "memory");                       \
        __builtin_amdgcn_s_barrier();                                          \
        __builtin_amdgcn_sched_barrier(0);                                     \
        G1_COMPUTE(_cur);                                                      \
        __builtin_amdgcn_sched_barrier(0);                                     \
        __builtin_amdgcn_s_barrier();                                          \
        __builtin_amdgcn_sched_barrier(0);                                     \
    }

    const int nk = K / 32;                 // 32
    G1_STAGE(0, 0);
    G1_STAGE(1, 1);

    for (int t = 0; t < nk - 2; ++t)
        G1_KSTEP(t, "vmcnt(4)");
    G1_KSTEP(nk - 2, "vmcnt(2)");
    G1_KSTEP(nk - 1, "vmcnt(0)");

#undef G1_KSTEP
#undef G1_COMPUTE
#undef G1_STAGE

    // ---- epilogue: 64-col region (64-aligned) mod 192 selects Q/K/V of head h
    const int colb = n0 + wc * 64;
    const int kind = (colb >> 6) % 3;      // 0=Q, 1=K, 2=V
    const int h    = colb / 192;
    const int bb   = m0 >> 11;             // batch = row/2048 (tile within one batch)
    const int m0r  = m0 & 2047;            // s base within batch
    const size_t hsz = (size_t)8 * SEQ * 8;

    if (kind == 0) {
        // Q -> q_h[4096][1024]: row-major, head-compacted
        _Float16* qh = Qh + (size_t)m0 * D_MODEL + h * HDIM;
        #pragma unroll
        for (int nt = 0; nt < 4; ++nt) {
            const float bv = bias[colb + nt * 16 + l16];
            #pragma unroll
            for (int mt = 0; mt < 2; ++mt) {
                #pragma unroll
                for (int r = 0; r < 4; ++r) {
                    const int row = wr * 32 + mt * 16 + quad * 4 + r;
                    qh[(size_t)row * D_MODEL + nt * 16 + l16] = (_Float16)(acc[mt][nt][r] + bv);
                }
            }
        }
    } else if (kind == 1) {
        // K(s,d) -> kh[(d>>3)*SEQ*8 + s*8 + (d&7)]
        _Float16* kh = Ksw + (size_t)(bb * NHEAD + h) * hsz;
        #pragma unroll
        for (int nt = 0; nt < 4; ++nt) {
            const int d = nt * 16 + l16;
            const float bv = bias[colb + nt * 16 + l16];
            _Float16* kd = kh + (size_t)(d >> 3) * (SEQ * 8) + (d & 7);
            #pragma unroll
            for (int mt = 0; mt < 2; ++mt) {
                #pragma unroll
                for (int r = 0; r < 4; ++r) {
                    const int s = m0r + wr * 32 + mt * 16 + quad * 4 + r;
                    kd[(size_t)s * 8] = (_Float16)(acc[mt][nt][r] + bv);
                }
            }
        }
    } else {
        // V(s,d) -> vh[(s>>3)*512 + d*8 + (s&7)]; 4 acc rows = contiguous f16x4
        _Float16* vh = Vsw + (size_t)(bb * NHEAD + h) * hsz;
        #pragma unroll
        for (int nt = 0; nt < 4; ++nt) {
            const int d = nt * 16 + l16;
            const float bv = bias[colb + nt * 16 + l16];
            #pragma unroll
            for (int mt = 0; mt < 2; ++mt) {
                const int s0 = m0r + wr * 32 + mt * 16 + quad * 4;
                f16x4 pk;
                #pragma unroll
                for (int r = 0; r < 4; ++r)
                    pk[r] = (_Float16)(acc[mt][nt][r] + bv);
                *(f16x4*)&vh[(size_t)(s0 >> 3) * 512 + d * 8 + (s0 & 7)] = pk;
            }
        }
    }
}

// ---------------- GEMM2: 128x64 tile, BK=32, 512 threads (8 waves of 32x32),
//                  double-buffered staging, one barrier per K-step, fp32 out --
__global__ __launch_bounds__(512) void gemm_out_kernel(
    const _Float16* __restrict__ A, const _Float16* __restrict__ Bt,
    const float* __restrict__ bias, float* __restrict__ Cout)
{
    const int K = D_MODEL, N = D_MODEL;
    __shared__ _Float16 ldsA[2][4096];    // [buf][chunk4][row128][8] 8KB x2
    __shared__ _Float16 ldsB[2][2048];    // [buf][chunk4][row64][8]  4KB x2
    const int tid = threadIdx.x;
    const int wave = tid >> 6, lane = tid & 63;
    const int quad = lane >> 4, l16 = lane & 15;
    const int m0 = blockIdx.y * 128, n0 = blockIdx.x * 64;
    const int wr = wave >> 1, wc = wave & 1;       // wave tile: rows wr*32, cols wc*32

    f32x4 acc[2][2] = {};

    // prologue: stage K-tile 0 into buf 0
    if (wave < 4) {
        #pragma unroll
        for (int j = 0; j < 2; ++j) {
            const int seg = wave * 2 + j;
            const int chunk = seg >> 1;
            const int row = ((seg & 1) << 6) | lane;
            GLOBAL_LOAD_LDS16(A + (size_t)(m0 + row) * K + chunk * 8, &ldsA[0][seg * 512]);
        }
    } else {
        const int seg = wave - 4;
        GLOBAL_LOAD_LDS16(Bt + (size_t)(n0 + lane) * K + seg * 8, &ldsB[0][seg * 512]);
    }
    __syncthreads();

    const int nk = K / 32;
    for (int t = 0; t < nk; ++t) {
        const int cur = t & 1;

        if (t + 1 < nk) {
            const int k1 = (t + 1) * 32;
            if (wave < 4) {
                #pragma unroll
                for (int j = 0; j < 2; ++j) {
                    const int seg = wave * 2 + j;
                    const int chunk = seg >> 1;
                    const int row = ((seg & 1) << 6) | lane;
                    GLOBAL_LOAD_LDS16(A + (size_t)(m0 + row) * K + k1 + chunk * 8,
                                      &ldsA[cur ^ 1][seg * 512]);
                }
            } else {
                const int seg = wave - 4;
                GLOBAL_LOAD_LDS16(Bt + (size_t)(n0 + lane) * K + k1 + seg * 8,
                                  &ldsB[cur ^ 1][seg * 512]);
            }
        }

        f16x8 a[2], b[2];
        #pragma unroll
        for (int mt = 0; mt < 2; ++mt)
            a[mt] = *(const f16x8*)&ldsA[cur][quad * 1024 + (wr * 32 + mt * 16 + l16) * 8];
        #pragma unroll
        for (int nt = 0; nt < 2; ++nt)
            b[nt] = *(const f16x8*)&ldsB[cur][quad * 512 + (wc * 32 + nt * 16 + l16) * 8];
        #pragma unroll
        for (int mt = 0; mt < 2; ++mt)
            #pragma unroll
            for (int nt = 0; nt < 2; ++nt)
                acc[mt][nt] = __builtin_amdgcn_mfma_f32_16x16x32_f16(a[mt], b[nt], acc[mt][nt], 0, 0, 0);

        __syncthreads();
    }

    #pragma unroll
    for (int nt = 0; nt < 2; ++nt) {
        const int col = n0 + wc * 32 + nt * 16 + l16;
        const float bv = bias[col];
        #pragma unroll
        for (int mt = 0; mt < 2; ++mt) {
            #pragma unroll
            for (int r = 0; r < 4; ++r) {
                const int row = m0 + wr * 32 + mt * 16 + quad * 4 + r;
                Cout[(size_t)row * N + col] = acc[mt][nt][r] + bv;
            }
        }
    }
}

// softmax fragment: s0/s1 (keys 0-31 / 32-63 scores for q=l31) -> 4 PV A-frags
// pa[ks][j] = P[q=l31][key = ks*16 + hi*8 + j], rs += sum of own 32 exp2's.
__device__ __forceinline__ void softmax_frag(
    const f32x16 s0, const f32x16 s1, float& rs, f16x8 pa[4])
{
    #pragma unroll
    for (int half = 0; half < 2; ++half) {
        const f32x16 sv = half ? s1 : s0;
        float p[16];
        #pragma unroll
        for (int r = 0; r < 16; ++r)
            p[r] = __builtin_amdgcn_exp2f(sv[r]);
        #pragma unroll
        for (int r = 0; r < 16; r += 4)
            rs += (p[r] + p[r + 1]) + (p[r + 2] + p[r + 3]);

        union { f16x8 hv; unsigned u[4]; } lo, hh;
        {
            const unsigned A = __builtin_bit_cast(unsigned, __builtin_amdgcn_cvt_pkrtz(p[0], p[1]));
            const unsigned B = __builtin_bit_cast(unsigned, __builtin_amdgcn_cvt_pkrtz(p[2], p[3]));
            const unsigned C = __builtin_bit_cast(unsigned, __builtin_amdgcn_cvt_pkrtz(p[4], p[5]));
            const unsigned D = __builtin_bit_cast(unsigned, __builtin_amdgcn_cvt_pkrtz(p[6], p[7]));
            const auto rac = __builtin_amdgcn_permlane32_swap(A, C, false, false);
            const auto rbd = __builtin_amdgcn_permlane32_swap(B, D, false, false);
            lo.u[0] = rac[0]; lo.u[1] = rbd[0]; lo.u[2] = rac[1]; lo.u[3] = rbd[1];
        }
        {
            const unsigned E = __builtin_bit_cast(unsigned, __builtin_amdgcn_cvt_pkrtz(p[8],  p[9]));
            const unsigned F = __builtin_bit_cast(unsigned, __builtin_amdgcn_cvt_pkrtz(p[10], p[11]));
            const unsigned G = __builtin_bit_cast(unsigned, __builtin_amdgcn_cvt_pkrtz(p[12], p[13]));
            const unsigned H = __builtin_bit_cast(unsigned, __builtin_amdgcn_cvt_pkrtz(p[14], p[15]));
            const auto reg = __builtin_amdgcn_permlane32_swap(E, G, false, false);
            const auto rfh = __builtin_amdgcn_permlane32_swap(F, H, false, false);
            hh.u[0] = reg[0]; hh.u[1] = rfh[0]; hh.u[2] = reg[1]; hh.u[3] = rfh[1];
        }
        pa[half * 2]     = lo.hv;
        pa[half * 2 + 1] = hh.hv;
    }
}

// ---------------- fp16 MFMA flash attention, 32x32, QBLK=256 (8 waves x 32q),
//                  KVBLK=128 (2x 64-key subtiles per barrier), dbuf K/V --------
__global__ __launch_bounds__(512) void attn_mfma_kernel(
    const _Float16* __restrict__ Qh,
    const _Float16* __restrict__ Ksw, const _Float16* __restrict__ Vsw,
    _Float16* __restrict__ val)
{
    __shared__ _Float16 Ks[2][8192];      // [sub2][dchunk8][key64][8]  16KB x2
    __shared__ _Float16 Vts[2][8192];     // [sub2][kchunk8][d64][8]    16KB x2

    const int tid = threadIdx.x;
    const int wave = tid >> 6, lane = tid & 63;
    const int l31 = lane & 31, hi = lane >> 5;

    // XCD-chunked swizzle: 256 blocks, 32/XCD = 4 heads x 8 qt -> K/V 2MB/XCD
    const int id = blockIdx.x;
    const int g  = (id & 7) * 32 + (id >> 3);
    const int qt = g & 7, hb = g >> 3;
    const int h  = hb & 15, b = hb >> 4;
    const int q0 = qt * 256;

    const size_t hsz = (size_t)8 * SEQ * 8;
    const _Float16* kh = Ksw + (size_t)(b * NHEAD + h) * hsz;
    const _Float16* vh = Vsw + (size_t)(b * NHEAD + h) * hsz;

    // Q B-fragments: col=l31 -> q row, k = kk*16 + hi*8 + j  (from compact q_h)
    f16x8 qf[4];
    {
        const int row = q0 + wave * 32 + l31;
        const _Float16* src = Qh + (size_t)(b * SEQ + row) * D_MODEL + h * HDIM + hi * 8;
        #pragma unroll
        for (int kk = 0; kk < 4; ++kk) {
            const f16x8 t = *(const f16x8*)(src + kk * 16);
            #pragma unroll
            for (int j = 0; j < 8; ++j)
                qf[kk][j] = (_Float16)((float)t[j] * 0.1803368802f);   // (1/8)*log2(e)
        }
    }

    f32x16 acc0 = {};      // O[q][d], dtile 0 (d = l31)
    f32x16 acc1 = {};      // dtile 1 (d = 32+l31)
    float rs = 0.f;

    // staging: 8 waves x 2 chunk-instrs each cover sub(2) x chunk(8) for K and V
    const int sidx0 = wave * 2;            // 0..14 even
    // prologue: stage 128-key tile 0 into buffer 0
    #pragma unroll
    for (int j = 0; j < 2; ++j) {
        const int idx = sidx0 + j;         // 0..15
        const int u = idx >> 3, c = idx & 7;
        GLOBAL_LOAD_LDS16(kh + ((size_t)c * SEQ + u * 64 + lane) * 8, &Ks[0][idx * 512]);
        GLOBAL_LOAD_LDS16(vh + ((size_t)(u * 8 + c) * HDIM + lane) * 8, &Vts[0][idx * 512]);
    }
    __syncthreads();

    for (int kt = 0; kt < SEQ / 128; ++kt) {
        const int cur = kt & 1;

        // stage tile kt+1 into the other buffer
        if (kt + 1 < SEQ / 128) {
            #pragma unroll
            for (int j = 0; j < 2; ++j) {
                const int idx = sidx0 + j;
                const int u = idx >> 3, c = idx & 7;
                GLOBAL_LOAD_LDS16(kh + ((size_t)c * SEQ + (kt + 1) * 128 + u * 64 + lane) * 8,
                                  &Ks[cur ^ 1][idx * 512]);
                GLOBAL_LOAD_LDS16(vh + ((size_t)((kt + 1) * 16 + u * 8 + c) * HDIM + lane) * 8,
                                  &Vts[cur ^ 1][idx * 512]);
            }
        }

        // ---- two 64-key subtiles ----
        #pragma unroll
        for (int u = 0; u < 2; ++u) {
            const _Float16* ksub = &Ks[cur][u * 4096];
            const _Float16* vsub = &Vts[cur][u * 4096];

            // QK^T: S^T tiles (keytile 0: keys 0-31, keytile 1: keys 32-63)
            f32x16 s0 = {}, s1 = {};
            __builtin_amdgcn_s_setprio(1);
            #pragma unroll
            for (int kk = 0; kk < 4; ++kk) {
                const f16x8 k0 = *(const f16x8*)&ksub[(kk * 2 + hi) * 512 + l31 * 8];
                const f16x8 k1 = *(const f16x8*)&ksub[(kk * 2 + hi) * 512 + (32 + l31) * 8];
                s0 = __builtin_amdgcn_mfma_f32_32x32x16_f16(k0, qf[kk], s0, 0, 0, 0);
                s1 = __builtin_amdgcn_mfma_f32_32x32x16_f16(k1, qf[kk], s1, 0, 0, 0);
            }
            __builtin_amdgcn_s_setprio(0);

            // exp2 + in-register transpose to PV A-frags
            f16x8 pa[4];
            softmax_frag(s0, s1, rs, pa);

            // PV: O[q][d] += P[q][k] V[k][d], 4 ksteps of 16 keys
            __builtin_amdgcn_s_setprio(1);
            #pragma unroll
            for (int ks = 0; ks < 4; ++ks) {
                const f16x8 v0 = *(const f16x8*)&vsub[(ks * 2 + hi) * 512 + l31 * 8];
                const f16x8 v1 = *(const f16x8*)&vsub[(ks * 2 + hi) * 512 + (32 + l31) * 8];
                acc0 = __builtin_amdgcn_mfma_f32_32x32x16_f16(pa[ks], v0, acc0, 0, 0, 0);
                acc1 = __builtin_amdgcn_mfma_f32_32x32x16_f16(pa[ks], v1, acc1, 0, 0, 0);
            }
            __builtin_amdgcn_s_setprio(0);
        }

        __syncthreads();
    }

    // lane covers half the keys for q=l31; partner lane^32 has the complement
    rs += __shfl_xor(rs, 32);
    const float inv = 1.f / rs;

    #pragma unroll
    for (int r = 0; r < 16; ++r) {
        const int qo = (r & 3) + 8 * (r >> 2) + 4 * hi;     // wave-local q row
        const float invr = __shfl(inv, qo);                  // lane qo holds inv for q=qo
        const int row = b * SEQ + q0 + wave * 32 + qo;
        val[(size_t)row * D_MODEL + h * HDIM + l31]      = (_Float16)(acc0[r] * invr);
        val[(size_t)row * D_MODEL + h * HDIM + 32 + l31] = (_Float16)(acc1[r] * invr);
    }
}

extern "C" void kernel_launch(void* const* d_in, const int* in_sizes, int n_in,
                              void* d_out, int out_size, void* d_ws, size_t ws_size,
                              hipStream_t stream)
{
    const float* x     = (const float*)d_in[0];
    const float* W_qkv = (const float*)d_in[1];
    const float* b_qkv = (const float*)d_in[2];
    const float* W_out = (const float*)d_in[3];
    const float* b_out = (const float*)d_in[4];

    char* ws = (char*)d_ws;
    _Float16* Ksw   = (_Float16*)ws;                      // [32][8][2048][8]  8 MiB
    _Float16* val_h = (_Float16*)(ws + (8u << 20));       // [4096][1024]      8 MiB
    _Float16* wq_t  = (_Float16*)(ws + (16u << 20));      // [3072][1024]      6 MiB
    _Float16* wo_t  = (_Float16*)(ws + (22u << 20));      // [1024][1024]      2 MiB
    _Float16* q_h   = (_Float16*)(ws + (24u << 20));      // [4096][1024]      8 MiB
    _Float16* x_h   = (_Float16*)(ws + (32u << 20));      // [4096][1024]      8 MiB
    _Float16* Vsw   = (_Float16*)(ws + (40u << 20));      // [32][256][64][8]  8 MiB

    prep_kernel<<<5120, 256, 0, stream>>>(x, x_h, W_qkv, wq_t, W_out, wo_t);
    gemm_qkv_kernel<<<dim3(3 * D_MODEL / 128, NTOK / 128), 512, 0, stream>>>(
        x_h, wq_t, b_qkv, q_h, Ksw, Vsw, NTOK, 3 * D_MODEL, D_MODEL);
    attn_mfma_kernel<<<dim3(256, 1, 1), 512, 0, stream>>>(q_h, Ksw, Vsw, val_h);
    gemm_out_kernel<<<dim3(D_MODEL / 64, NTOK / 128), 512, 0, stream>>>(
        val_h, wo_t, b_out, (float*)d_out);
}